// Round 5
// baseline (147.121 us; speedup 1.0000x reference)
//
#include <hip/hip_runtime.h>
#include <math.h>

// Problem constants
#define H28 28
#define G784 784
#define BATCH 32
#define NOFF 3025   // 55*55 lattice offsets (|di|,|dj| <= 27)
#define NOFFP 3072  // padded to multiple of 64
#define NKEY 1459   // keys di*di+dj*dj in [0, 1458]
#define TPTS 25
#define KMAX 2
#define NFEAT 50    // KMAX*TPTS
#define OUTF 50
#define NCLS 10

#define NBX 28      // blocks per batch for dtm
#define BT 512      // threads per dtm block (8 waves)
#define BT2 64      // pd0: ONE WAVE per block -> barriers are waitcnt-only
#define HS 2048     // edge-dedup hash slots (pow2)
#define EMAX 1024   // deduped edge capacity (planar bound ~3*mcnt)
#define RMAX 16     // EMAX/64 edges held per lane in rank sort

// ---------------------------------------------------------------------------
// Compile-time counting-sorted offset table. d2 reproduces
// f32(sqrt(key)*(224/27))^2 via constexpr Newton sqrt in double.
// ---------------------------------------------------------------------------
struct OffPair { unsigned ij; float d2; };
struct OffTab  { OffPair e[NOFFP]; };

constexpr double csqrt(double x) {
  double r = x * 0.5 + 1.0;
  for (int i = 0; i < 20; i++) r = 0.5 * (r + x / r);
  return r;
}

constexpr OffTab make_offtab() {
  OffTab t{};
  int start[NKEY] = {};
  for (int i = 0; i < NOFF; i++) {
    int di = i / 55 - 27, dj = i % 55 - 27;
    start[di * di + dj * dj]++;
  }
  int run = 0;
  for (int k = 0; k < NKEY; k++) { int h = start[k]; start[k] = run; run += h; }
  for (int i = 0; i < NOFF; i++) {
    int di = i / 55 - 27, dj = i % 55 - 27;
    int key = di * di + dj * dj;
    int pos = start[key]++;
    float sd = (key == 0) ? 0.0f : (float)(csqrt((double)key) * (224.0 / 27.0));
    t.e[pos].ij = ((unsigned)(di & 0xffff)) | (((unsigned)(dj & 0xffff)) << 16);
    t.e[pos].d2 = sd * sd;
  }
  for (int i = NOFF; i < NOFFP; i++) { t.e[i].ij = 0x00640064u; t.e[i].d2 = 0.f; }
  return t;
}

__device__ constexpr OffTab OFFTAB = make_offtab();

// ---------------------------------------------------------------------------
// wave64 inclusive scan via DPP (row_shr 1,2,4,8; row_bcast15/31).
// ---------------------------------------------------------------------------
__device__ __forceinline__ float wave_iscan_f32(float x) {
  int t;
  t = __builtin_amdgcn_update_dpp(0, __float_as_int(x), 0x111, 0xf, 0xf, true);
  x += __int_as_float(t);
  t = __builtin_amdgcn_update_dpp(0, __float_as_int(x), 0x112, 0xf, 0xf, true);
  x += __int_as_float(t);
  t = __builtin_amdgcn_update_dpp(0, __float_as_int(x), 0x114, 0xf, 0xf, true);
  x += __int_as_float(t);
  t = __builtin_amdgcn_update_dpp(0, __float_as_int(x), 0x118, 0xf, 0xf, true);
  x += __int_as_float(t);
  t = __builtin_amdgcn_update_dpp(0, __float_as_int(x), 0x142, 0xa, 0xf, true);
  x += __int_as_float(t);
  t = __builtin_amdgcn_update_dpp(0, __float_as_int(x), 0x143, 0xc, 0xf, true);
  x += __int_as_float(t);
  return x;
}

// ---------------------------------------------------------------------------
// Kernel 1: DTM. grid=(BATCH,NBX), block=BT. One wave per pixel,
// 64 offsets/step, dual DPP prefix scans; 1-barrier block reduction.
// ---------------------------------------------------------------------------
__global__ __launch_bounds__(BT) void dtm_kernel(const float* __restrict__ x,
                                                 float* __restrict__ v,
                                                 int* __restrict__ done_ctr) {
  __shared__ float w_s[G784];
  __shared__ float red[BT / 64];

  const int tid  = threadIdx.x;
  const int b    = blockIdx.x;
  const int bx   = blockIdx.y;
  const int wave = tid >> 6;
  const int lane = tid & 63;

  if (b == 0 && bx == 0 && tid == 0) *done_ctr = 0;

  float ps = 0.f;
  for (int i = tid; i < G784; i += BT) {
    float wv = x[b * G784 + i];
    w_s[i] = wv;
    ps += wv;
  }
  for (int off = 32; off > 0; off >>= 1) ps += __shfl_xor(ps, off);
  if (lane == 0) red[wave] = ps;
  __syncthreads();
  float tot = 0.f;
  for (int k = 0; k < BT / 64; k++) tot += red[k];
  const float bound = 0.2f * tot;

  const int slot = bx * 8 + wave;       // 0..NBX*8-1

  for (int g = slot; g < G784; g += NBX * 8) {
    const int i1 = g / H28, j1 = g % H28;
    float cw = 0.f, cwd = 0.f;
    float cwp = 0.f, cwdp = 0.f, dk2 = 0.f;
    bool crossed = false;
    int o = lane;
    unsigned ij = OFFTAB.e[o].ij;
    float d2v   = OFFTAB.e[o].d2;
    for (int base = 0; base < NOFFP && !crossed; base += 64) {
      int onext = o + 64;
      if (onext >= NOFFP) onext = o;
      const unsigned ij_n = OFFTAB.e[onext].ij;
      const float    d2_n = OFFTAB.e[onext].d2;
      const int di = (short)(ij & 0xffffu);
      const int dj = (short)(ij >> 16);
      const int i2 = i1 + di, j2 = j1 + dj;
      const bool inb = ((unsigned)i2 < (unsigned)H28) & ((unsigned)j2 < (unsigned)H28);
      const float wv = inb ? w_s[i2 * H28 + j2] : 0.f;
      const float wd = wv * d2v;
      const float psw = wave_iscan_f32(wv);
      const float psd = wave_iscan_f32(wd);
      const unsigned long long mask = __ballot(cw + psw >= bound);
      if (mask) {
        const int f = __ffsll((unsigned long long)mask) - 1;
        const float psw_f = __shfl(psw, f);
        const float w_f   = __shfl(wv, f);
        const float psd_f = __shfl(psd, f);
        const float wd_f  = __shfl(wd, f);
        dk2  = __shfl(d2v, f);
        cwp  = cw + (psw_f - w_f);
        cwdp = cwd + (psd_f - wd_f);
        crossed = true;
      } else {
        cw  += __int_as_float(__builtin_amdgcn_readlane(__float_as_int(psw), 63));
        cwd += __int_as_float(__builtin_amdgcn_readlane(__float_as_int(psd), 63));
      }
      ij = ij_n; d2v = d2_n; o = onext;
    }
    const float val = (cwdp + (bound - cwp) * dk2) / bound;
    if (lane == 0) v[b * G784 + g] = sqrtf(fmaxf(val, 0.f));
  }
}

// ---------------------------------------------------------------------------
// Kernel 2: pd0 + landscape + (last block) dense head.
// grid=BATCH, block=64 (ONE WAVE: __syncthreads == s_waitcnt, no HW barrier).
// ---------------------------------------------------------------------------
__device__ __forceinline__ unsigned long long pix_key(const float* val_s, int p) {
  return (((unsigned long long)__float_as_uint(val_s[p])) << 10) | (unsigned)p;
}

__global__ __launch_bounds__(BT2) void pd0_kernel(const float* __restrict__ v,
                                                  float* __restrict__ feats,
                                                  int* __restrict__ done_ctr,
                                                  const float* __restrict__ w_land,
                                                  const float* __restrict__ b_land,
                                                  const float* __restrict__ w_fc,
                                                  const float* __restrict__ b_fc,
                                                  float* __restrict__ out) {
  __shared__ float val_s[G784];
  __shared__ int   ptr_s[G784];
  __shared__ int   parent[G784];
  __shared__ unsigned rank_s[G784];
  __shared__ unsigned claims[G784];
  __shared__ float deathv[G784];
  __shared__ int   mlist[G784];
  __shared__ unsigned long long oldkey[G784];
  __shared__ unsigned htag[HS];
  __shared__ unsigned long long hval[HS];   // hash vals; reused as sorted edges
  __shared__ unsigned long long edges[EMAX];
  __shared__ int   mcnt_sh, ecnt_sh, last_sh;
  __shared__ float xt_s[BATCH * OUTF];

  const int lane = threadIdx.x;             // 0..63, block IS one wave
  const int b    = blockIdx.x;
  if (lane == 0) { mcnt_sh = 0; ecnt_sh = 0; }

  for (int i = lane; i < HS; i += BT2) { htag[i] = 0u; hval[i] = ~0ULL; }

  float pm = -1e30f;
  for (int i = lane; i < G784; i += BT2) {
    float xv = v[b * G784 + i];
    val_s[i] = xv;
    pm = fmaxf(pm, xv);
    rank_s[i] = 0u;
    claims[i] = 0xFFFFFFFFu;
  }
  for (int off = 32; off > 0; off >>= 1) pm = fmaxf(pm, __shfl_xor(pm, off));
  const float vmax = pm;
  __syncthreads();

  // descending pointer forest; register minima
  for (int p = lane; p < G784; p += BT2) {
    unsigned long long kp = pix_key(val_s, p);
    int i = p / H28, j = p % H28;
    int nbs[4];
    nbs[0] = (i > 0)       ? p - H28 : -1;
    nbs[1] = (i < H28 - 1) ? p + H28 : -1;
    nbs[2] = (j > 0)       ? p - 1   : -1;
    nbs[3] = (j < H28 - 1) ? p + 1   : -1;
    int best = p;
    unsigned long long bk = kp;
    for (int t = 0; t < 4; t++) {
      int q = nbs[t];
      if (q >= 0) {
        unsigned long long kq = pix_key(val_s, q);
        if (kq < bk) { bk = kq; best = q; }
      }
    }
    ptr_s[p]  = best;
    parent[p] = p;
    deathv[p] = vmax;
    if (best == p) {
      oldkey[p] = kp;
      int mi = atomicAdd(&mcnt_sh, 1);
      mlist[mi] = p;
    }
  }
  __syncthreads();

  // pointer doubling -> basin roots (ballot early exit; races benign)
  for (int r = 0; r < 10; r++) {
    bool ch = false;
    for (int p = lane; p < G784; p += BT2) {
      int a = ptr_s[p];
      int c = ptr_s[a];
      if (a != c) { ptr_s[p] = c; ch = true; }
    }
    __syncthreads();
    if (__ballot(ch) == 0ULL) break;
  }

  // cross-basin edges -> hash dedup (per unordered basin pair keep min key)
  for (int p = lane; p < G784; p += BT2) {
    unsigned long long kp = pix_key(val_s, p);
    int i = p / H28, j = p % H28;
    int nbs[4];
    nbs[0] = (i > 0)       ? p - H28 : -1;
    nbs[1] = (i < H28 - 1) ? p + H28 : -1;
    nbs[2] = (j > 0)       ? p - 1   : -1;
    nbs[3] = (j < H28 - 1) ? p + 1   : -1;
    int bp = ptr_s[p];
    for (int t = 0; t < 4; t++) {
      int q = nbs[t];
      if (q >= 0) {
        unsigned long long kq = pix_key(val_s, q);
        int bq = ptr_s[q];
        if (kq < kp && bq != bp) {
          unsigned long long key =
              (((unsigned long long)__float_as_uint(val_s[p])) << 32) |
              (((unsigned long long)(unsigned)p) << 22) |
              (((unsigned long long)(unsigned)t) << 20) |
              (((unsigned long long)(unsigned)bp) << 10) |
              ((unsigned long long)(unsigned)bq);
          unsigned lo = (bp < bq) ? (unsigned)bp : (unsigned)bq;
          unsigned hi = (bp < bq) ? (unsigned)bq : (unsigned)bp;
          unsigned pairid = (lo << 10) | hi;
          unsigned idx = (pairid * 2654435761u) >> 21;   // HS=2048
          for (;;) {
            unsigned t0 = atomicCAS(&htag[idx], 0u, pairid + 1u);
            if (t0 == 0u || t0 == pairid + 1u) { atomicMin(&hval[idx], key); break; }
            idx = (idx + 1) & (HS - 1);
          }
        }
      }
    }
  }
  __syncthreads();

  // compact hash -> edges
  for (int i = lane; i < HS; i += BT2) {
    if (htag[i]) {
      int e = atomicAdd(&ecnt_sh, 1);
      if (e < EMAX) edges[e] = hval[i];
    }
  }
  __syncthreads();
  const int ne   = (ecnt_sh < EMAX) ? ecnt_sh : EMAX;
  const int mcnt = mcnt_sh;

  // ---- rank sort (keys unique): broadcast reads, no serial pass chain ----
  unsigned long long mine[RMAX];
  int rnk[RMAX];
  int cnt = 0;
  for (int i = lane; i < ne; i += BT2) { mine[cnt] = edges[i]; rnk[cnt] = 0; cnt++; }
  for (int j = 0; j < ne; j++) {
    unsigned long long ej = edges[j];     // broadcast LDS read
    for (int k = 0; k < cnt; k++) rnk[k] += (ej < mine[k]) ? 1 : 0;
  }
  for (int k = 0; k < cnt; k++) hval[rnk[k]] = mine[k];
  __syncthreads();
  const unsigned long long* sedges = hval; // sorted ascending

  // ---- claim-based parallel Kruskal, exact sequential-order semantics ----
  {
    int merged = 0;
    const int target = mcnt - 1;
    for (int base = 0; base < ne && merged < target; base += 64) {
      const int idx = base + lane;
      bool unresolved = (idx < ne);
      const unsigned long long e = unresolved ? sedges[idx] : 0ULL;
      const int A  = (int)((e >> 10) & 1023u);
      const int Bq = (int)(e & 1023u);
      const float ev = __uint_as_float((unsigned)(e >> 32));
      for (;;) {
        int rA = A, rB = Bq;
        if (unresolved) {
          int xx = A;
          for (;;) { int p1 = parent[xx]; if (p1 == xx) break;
                     int p2 = parent[p1]; parent[xx] = p2; xx = p2; }
          rA = xx;
          xx = Bq;
          for (;;) { int p1 = parent[xx]; if (p1 == xx) break;
                     int p2 = parent[p1]; parent[xx] = p2; xx = p2; }
          rB = xx;
        }
        bool crossing = unresolved && (rA != rB);
        if (unresolved && !crossing) unresolved = false;
        if (__ballot(crossing) == 0ULL) break;
        if (crossing) {
          atomicMin(&claims[rA], (unsigned)lane);
          atomicMin(&claims[rB], (unsigned)lane);
        }
        __syncthreads();
        bool win = crossing && claims[rA] == (unsigned)lane
                            && claims[rB] == (unsigned)lane;
        __syncthreads();
        if (crossing) { claims[rA] = 0xFFFFFFFFu; claims[rB] = 0xFFFFFFFFu; }
        if (win) {
          unsigned long long ka = oldkey[rA], kb = oldkey[rB];
          unsigned ra_ = rank_s[rA], rb_ = rank_s[rB];
          int big   = (ra_ > rb_) ? rA : ((rb_ > ra_) ? rB : ((rA < rB) ? rA : rB));
          int small = (big == rA) ? rB : rA;
          parent[small] = big;
          if (ra_ == rb_) rank_s[big] = ra_ + 1u;
          unsigned long long okmin = (ka < kb) ? ka : kb;
          unsigned long long okmax = (ka < kb) ? kb : ka;
          oldkey[big] = okmin;
          int dying = (int)(okmax & 1023u);
          deathv[dying] = ev;
          unresolved = false;
        }
        __syncthreads();
        merged += (int)__popcll(__ballot(win));
        if (merged >= target) break;
      }
    }
  }
  __syncthreads();

  // landscape features: top-2 tents over minima per t (lanes 0..24)
  if (lane < TPTS) {
    float ti = (float)((double)lane * (100.0 / 24.0));
    float t1 = 0.f, t2 = 0.f;
    for (int ii = 0; ii < mcnt; ii++) {
      int m = mlist[ii];
      float tent = fminf(ti - val_s[m], deathv[m] - ti);
      tent = fmaxf(tent, 0.f);
      if (tent > t1)      { t2 = t1; t1 = tent; }
      else if (tent > t2) { t2 = tent; }
    }
    feats[b * NFEAT + lane]        = t1;
    feats[b * NFEAT + TPTS + lane] = t2;
  }

  // ---- last block computes the dense head ----
  __threadfence();
  __syncthreads();
  if (lane == 0) last_sh = (atomicAdd(done_ctr, 1) == BATCH - 1) ? 1 : 0;
  __syncthreads();
  if (!last_sh) return;
  __threadfence();

  for (int idx = lane; idx < BATCH * OUTF; idx += BT2) {
    int bb = idx / OUTF, ff = idx % OUTF;
    float acc = b_land[ff];
    const float* wr = w_land + ff * NFEAT;
    const float* fr = feats + bb * NFEAT;
    for (int j = 0; j < NFEAT; j++) acc += fr[j] * wr[j];
    xt_s[idx] = acc;
  }
  __syncthreads();
  if (lane < OUTF) {
    float s = 0.f;
    for (int bb = 0; bb < BATCH; bb++) s += fabsf(xt_s[bb * OUTF + lane]);
    out[BATCH * NCLS + lane] = s;
  }
  for (int idx = lane; idx < BATCH * NCLS; idx += BT2) {
    int bb = idx / NCLS, cc = idx % NCLS;
    float acc = b_fc[cc];
    const float* wr = w_fc + cc * OUTF;
    const float* xr = xt_s + bb * OUTF;
    for (int ff = 0; ff < OUTF; ff++) acc += fmaxf(xr[ff], 0.f) * wr[ff];
    out[bb * NCLS + cc] = acc;
  }
}

// ---------------------------------------------------------------------------
extern "C" void kernel_launch(void* const* d_in, const int* in_sizes, int n_in,
                              void* d_out, int out_size, void* d_ws, size_t ws_size,
                              hipStream_t stream) {
  (void)in_sizes; (void)n_in; (void)out_size; (void)ws_size;
  const float* x      = (const float*)d_in[0];   // [32,1,28,28]
  const float* w_land = (const float*)d_in[1];   // [50,50]
  const float* b_land = (const float*)d_in[2];   // [50]
  const float* w_fc   = (const float*)d_in[3];   // [10,50]
  const float* b_fc   = (const float*)d_in[4];   // [10]
  float* out   = (float*)d_out;                  // [32*10] out then [50] signal
  float* v     = (float*)d_ws;                   // [32*784]
  float* feats = v + BATCH * G784;               // [32*50]
  int*   done  = (int*)(feats + BATCH * NFEAT);  // [1]

  dim3 g1(BATCH, NBX);
  dtm_kernel<<<g1, BT, 0, stream>>>(x, v, done);
  pd0_kernel<<<BATCH, BT2, 0, stream>>>(v, feats, done,
                                        w_land, b_land, w_fc, b_fc, out);
}

// Round 6
// 102.699 us; speedup vs baseline: 1.4326x; 1.4326x over previous
//
#include <hip/hip_runtime.h>
#include <math.h>

// Problem constants
#define H28 28
#define G784 784
#define BATCH 32
#define NOFF 3025   // 55*55 lattice offsets (|di|,|dj| <= 27)
#define NOFFP 3072  // padded to multiple of 64
#define NKEY 1459   // keys di*di+dj*dj in [0, 1458]
#define TPTS 25
#define KMAX 2
#define NFEAT 50    // KMAX*TPTS
#define OUTF 50
#define NCLS 10

#define NBX 28      // blocks per batch for dtm
#define BT 512      // threads per dtm block (8 waves)
#define BT2 512     // pd0 block: 8 waves (latency hiding across waves!)
#define HS 2048     // edge-dedup hash slots (pow2)
#define EMAX 1024   // deduped edge capacity (planar bound ~3*mcnt)

// ---------------------------------------------------------------------------
// Compile-time counting-sorted offset table. d2 reproduces
// f32(sqrt(key)*(224/27))^2 via constexpr Newton sqrt in double.
// ---------------------------------------------------------------------------
struct OffPair { unsigned ij; float d2; };
struct OffTab  { OffPair e[NOFFP]; };

constexpr double csqrt(double x) {
  double r = x * 0.5 + 1.0;
  for (int i = 0; i < 20; i++) r = 0.5 * (r + x / r);
  return r;
}

constexpr OffTab make_offtab() {
  OffTab t{};
  int start[NKEY] = {};
  for (int i = 0; i < NOFF; i++) {
    int di = i / 55 - 27, dj = i % 55 - 27;
    start[di * di + dj * dj]++;
  }
  int run = 0;
  for (int k = 0; k < NKEY; k++) { int h = start[k]; start[k] = run; run += h; }
  for (int i = 0; i < NOFF; i++) {
    int di = i / 55 - 27, dj = i % 55 - 27;
    int key = di * di + dj * dj;
    int pos = start[key]++;
    float sd = (key == 0) ? 0.0f : (float)(csqrt((double)key) * (224.0 / 27.0));
    t.e[pos].ij = ((unsigned)(di & 0xffff)) | (((unsigned)(dj & 0xffff)) << 16);
    t.e[pos].d2 = sd * sd;
  }
  for (int i = NOFF; i < NOFFP; i++) { t.e[i].ij = 0x00640064u; t.e[i].d2 = 0.f; }
  return t;
}

__device__ constexpr OffTab OFFTAB = make_offtab();

// ---------------------------------------------------------------------------
// wave64 inclusive scan via DPP (row_shr 1,2,4,8; row_bcast15/31).
// ---------------------------------------------------------------------------
__device__ __forceinline__ float wave_iscan_f32(float x) {
  int t;
  t = __builtin_amdgcn_update_dpp(0, __float_as_int(x), 0x111, 0xf, 0xf, true);
  x += __int_as_float(t);
  t = __builtin_amdgcn_update_dpp(0, __float_as_int(x), 0x112, 0xf, 0xf, true);
  x += __int_as_float(t);
  t = __builtin_amdgcn_update_dpp(0, __float_as_int(x), 0x114, 0xf, 0xf, true);
  x += __int_as_float(t);
  t = __builtin_amdgcn_update_dpp(0, __float_as_int(x), 0x118, 0xf, 0xf, true);
  x += __int_as_float(t);
  t = __builtin_amdgcn_update_dpp(0, __float_as_int(x), 0x142, 0xa, 0xf, true);
  x += __int_as_float(t);
  t = __builtin_amdgcn_update_dpp(0, __float_as_int(x), 0x143, 0xc, 0xf, true);
  x += __int_as_float(t);
  return x;
}

// ---------------------------------------------------------------------------
// Kernel 1: DTM (unchanged from round 5). grid=(BATCH,NBX), block=BT.
// ---------------------------------------------------------------------------
__global__ __launch_bounds__(BT) void dtm_kernel(const float* __restrict__ x,
                                                 float* __restrict__ v,
                                                 int* __restrict__ done_ctr) {
  __shared__ float w_s[G784];
  __shared__ float red[BT / 64];

  const int tid  = threadIdx.x;
  const int b    = blockIdx.x;
  const int bx   = blockIdx.y;
  const int wave = tid >> 6;
  const int lane = tid & 63;

  if (b == 0 && bx == 0 && tid == 0) *done_ctr = 0;

  float ps = 0.f;
  for (int i = tid; i < G784; i += BT) {
    float wv = x[b * G784 + i];
    w_s[i] = wv;
    ps += wv;
  }
  for (int off = 32; off > 0; off >>= 1) ps += __shfl_xor(ps, off);
  if (lane == 0) red[wave] = ps;
  __syncthreads();
  float tot = 0.f;
  for (int k = 0; k < BT / 64; k++) tot += red[k];
  const float bound = 0.2f * tot;

  const int slot = bx * 8 + wave;

  for (int g = slot; g < G784; g += NBX * 8) {
    const int i1 = g / H28, j1 = g % H28;
    float cw = 0.f, cwd = 0.f;
    float cwp = 0.f, cwdp = 0.f, dk2 = 0.f;
    bool crossed = false;
    int o = lane;
    unsigned ij = OFFTAB.e[o].ij;
    float d2v   = OFFTAB.e[o].d2;
    for (int base = 0; base < NOFFP && !crossed; base += 64) {
      int onext = o + 64;
      if (onext >= NOFFP) onext = o;
      const unsigned ij_n = OFFTAB.e[onext].ij;
      const float    d2_n = OFFTAB.e[onext].d2;
      const int di = (short)(ij & 0xffffu);
      const int dj = (short)(ij >> 16);
      const int i2 = i1 + di, j2 = j1 + dj;
      const bool inb = ((unsigned)i2 < (unsigned)H28) & ((unsigned)j2 < (unsigned)H28);
      const float wv = inb ? w_s[i2 * H28 + j2] : 0.f;
      const float wd = wv * d2v;
      const float psw = wave_iscan_f32(wv);
      const float psd = wave_iscan_f32(wd);
      const unsigned long long mask = __ballot(cw + psw >= bound);
      if (mask) {
        const int f = __ffsll((unsigned long long)mask) - 1;
        const float psw_f = __shfl(psw, f);
        const float w_f   = __shfl(wv, f);
        const float psd_f = __shfl(psd, f);
        const float wd_f  = __shfl(wd, f);
        dk2  = __shfl(d2v, f);
        cwp  = cw + (psw_f - w_f);
        cwdp = cwd + (psd_f - wd_f);
        crossed = true;
      } else {
        cw  += __int_as_float(__builtin_amdgcn_readlane(__float_as_int(psw), 63));
        cwd += __int_as_float(__builtin_amdgcn_readlane(__float_as_int(psd), 63));
      }
      ij = ij_n; d2v = d2_n; o = onext;
    }
    const float val = (cwdp + (bound - cwp) * dk2) / bound;
    if (lane == 0) v[b * G784 + g] = sqrtf(fmaxf(val, 0.f));
  }
}

// ---------------------------------------------------------------------------
// Kernel 2: pd0 + landscape + (last block) dense head. grid=BATCH, block=512.
// Data-parallel phases use all 8 waves (latency hiding); rank-sort uses the
// full block; claim-Kruskal runs on wave 0 (serial-order semantics).
// ---------------------------------------------------------------------------
__device__ __forceinline__ unsigned long long pix_key(const float* val_s, int p) {
  return (((unsigned long long)__float_as_uint(val_s[p])) << 10) | (unsigned)p;
}

__global__ __launch_bounds__(BT2) void pd0_kernel(const float* __restrict__ v,
                                                  float* __restrict__ feats,
                                                  int* __restrict__ done_ctr,
                                                  const float* __restrict__ w_land,
                                                  const float* __restrict__ b_land,
                                                  const float* __restrict__ w_fc,
                                                  const float* __restrict__ b_fc,
                                                  float* __restrict__ out) {
  __shared__ float val_s[G784];
  __shared__ int   ptr_s[G784];
  __shared__ int   parent[G784];
  __shared__ unsigned rank_s[G784];
  __shared__ unsigned claims[G784];
  __shared__ float deathv[G784];
  __shared__ int   mlist[G784];
  __shared__ unsigned long long oldkey[G784];
  __shared__ unsigned htag[HS];
  __shared__ unsigned long long hval[HS];   // hash vals; reused as sorted edges
  __shared__ unsigned long long edges[EMAX];
  __shared__ float redf[BT2 / 64];
  __shared__ int   mcnt_sh, ecnt_sh, last_sh;
  __shared__ float xt_s[BATCH * OUTF];

  const int tid  = threadIdx.x;
  const int b    = blockIdx.x;
  const int wave = tid >> 6;
  const int lane = tid & 63;
  if (tid == 0) { mcnt_sh = 0; ecnt_sh = 0; }

  for (int i = tid; i < HS; i += BT2) { htag[i] = 0u; hval[i] = ~0ULL; }

  float pm = -1e30f;
  for (int i = tid; i < G784; i += BT2) {
    float xv = v[b * G784 + i];
    val_s[i] = xv;
    pm = fmaxf(pm, xv);
    rank_s[i] = 0u;
    claims[i] = 0xFFFFFFFFu;
  }
  for (int off = 32; off > 0; off >>= 1) pm = fmaxf(pm, __shfl_xor(pm, off));
  if (lane == 0) redf[wave] = pm;
  __syncthreads();
  float vmax = redf[0];
  for (int k = 1; k < BT2 / 64; k++) vmax = fmaxf(vmax, redf[k]);

  // descending pointer forest; register minima
  for (int p = tid; p < G784; p += BT2) {
    unsigned long long kp = pix_key(val_s, p);
    int i = p / H28, j = p % H28;
    int nbs[4];
    nbs[0] = (i > 0)       ? p - H28 : -1;
    nbs[1] = (i < H28 - 1) ? p + H28 : -1;
    nbs[2] = (j > 0)       ? p - 1   : -1;
    nbs[3] = (j < H28 - 1) ? p + 1   : -1;
    int best = p;
    unsigned long long bk = kp;
    for (int t = 0; t < 4; t++) {
      int q = nbs[t];
      if (q >= 0) {
        unsigned long long kq = pix_key(val_s, q);
        if (kq < bk) { bk = kq; best = q; }
      }
    }
    ptr_s[p]  = best;
    parent[p] = p;
    deathv[p] = vmax;
    if (best == p) {
      oldkey[p] = kp;
      int mi = atomicAdd(&mcnt_sh, 1);
      mlist[mi] = p;
    }
  }
  __syncthreads();

  // pointer doubling -> basin roots (10 rounds covers depth 1024)
  for (int r = 0; r < 10; r++) {
    for (int p = tid; p < G784; p += BT2) ptr_s[p] = ptr_s[ptr_s[p]];
    __syncthreads();
  }

  // cross-basin edges -> hash dedup (per unordered basin pair keep min key)
  for (int p = tid; p < G784; p += BT2) {
    unsigned long long kp = pix_key(val_s, p);
    int i = p / H28, j = p % H28;
    int nbs[4];
    nbs[0] = (i > 0)       ? p - H28 : -1;
    nbs[1] = (i < H28 - 1) ? p + H28 : -1;
    nbs[2] = (j > 0)       ? p - 1   : -1;
    nbs[3] = (j < H28 - 1) ? p + 1   : -1;
    int bp = ptr_s[p];
    for (int t = 0; t < 4; t++) {
      int q = nbs[t];
      if (q >= 0) {
        unsigned long long kq = pix_key(val_s, q);
        int bq = ptr_s[q];
        if (kq < kp && bq != bp) {
          unsigned long long key =
              (((unsigned long long)__float_as_uint(val_s[p])) << 32) |
              (((unsigned long long)(unsigned)p) << 22) |
              (((unsigned long long)(unsigned)t) << 20) |
              (((unsigned long long)(unsigned)bp) << 10) |
              ((unsigned long long)(unsigned)bq);
          unsigned lo = (bp < bq) ? (unsigned)bp : (unsigned)bq;
          unsigned hi = (bp < bq) ? (unsigned)bq : (unsigned)bp;
          unsigned pairid = (lo << 10) | hi;
          unsigned idx = (pairid * 2654435761u) >> 21;   // HS=2048
          for (;;) {
            unsigned t0 = atomicCAS(&htag[idx], 0u, pairid + 1u);
            if (t0 == 0u || t0 == pairid + 1u) { atomicMin(&hval[idx], key); break; }
            idx = (idx + 1) & (HS - 1);
          }
        }
      }
    }
  }
  __syncthreads();

  // compact hash -> edges
  for (int i = tid; i < HS; i += BT2) {
    if (htag[i]) {
      int e = atomicAdd(&ecnt_sh, 1);
      if (e < EMAX) edges[e] = hval[i];
    }
  }
  __syncthreads();
  const int ne   = (ecnt_sh < EMAX) ? ecnt_sh : EMAX;
  const int mcnt = mcnt_sh;

  // ---- full-block rank sort (keys unique; broadcast LDS reads pipeline) ----
  {
    unsigned long long m0 = 0, m1 = 0;
    int r0 = 0, r1 = 0;
    const int i0 = tid, i1 = tid + BT2;
    const bool h0 = (i0 < ne), h1 = (i1 < ne);
    if (h0) m0 = edges[i0];
    if (h1) m1 = edges[i1];
    for (int j = 0; j < ne; j++) {
      unsigned long long ej = edges[j];
      r0 += (ej < m0) ? 1 : 0;
      r1 += (ej < m1) ? 1 : 0;
    }
    if (h0) hval[r0] = m0;
    if (h1) hval[r1] = m1;
  }
  __syncthreads();
  const unsigned long long* sedges = hval;   // sorted ascending

  // ---- wave 0: claim-based parallel Kruskal (sequential-order exact) ----
  if (wave == 0) {
    int merged = 0;
    const int target = mcnt - 1;
    for (int base = 0; base < ne && merged < target; base += 64) {
      const int idx = base + lane;
      bool unresolved = (idx < ne);
      const unsigned long long e = unresolved ? sedges[idx] : 0ULL;
      const int A  = (int)((e >> 10) & 1023u);
      const int Bq = (int)(e & 1023u);
      const float ev = __uint_as_float((unsigned)(e >> 32));
      for (;;) {
        int rA = A, rB = Bq;
        if (unresolved) {
          int xx = A;
          for (;;) { int p1 = parent[xx]; if (p1 == xx) break;
                     int p2 = parent[p1]; parent[xx] = p2; xx = p2; }
          rA = xx;
          xx = Bq;
          for (;;) { int p1 = parent[xx]; if (p1 == xx) break;
                     int p2 = parent[p1]; parent[xx] = p2; xx = p2; }
          rB = xx;
        }
        bool crossing = unresolved && (rA != rB);
        if (unresolved && !crossing) unresolved = false;
        if (__ballot(crossing) == 0ULL) break;
        if (crossing) {
          atomicMin(&claims[rA], (unsigned)lane);
          atomicMin(&claims[rB], (unsigned)lane);
        }
        __threadfence_block();
        bool win = crossing && claims[rA] == (unsigned)lane
                            && claims[rB] == (unsigned)lane;
        __threadfence_block();
        if (crossing) { claims[rA] = 0xFFFFFFFFu; claims[rB] = 0xFFFFFFFFu; }
        if (win) {
          unsigned long long ka = oldkey[rA], kb = oldkey[rB];
          unsigned ra_ = rank_s[rA], rb_ = rank_s[rB];
          int big   = (ra_ > rb_) ? rA : ((rb_ > ra_) ? rB : ((rA < rB) ? rA : rB));
          int small = (big == rA) ? rB : rA;
          parent[small] = big;
          if (ra_ == rb_) rank_s[big] = ra_ + 1u;
          unsigned long long okmin = (ka < kb) ? ka : kb;
          unsigned long long okmax = (ka < kb) ? kb : ka;
          oldkey[big] = okmin;
          int dying = (int)(okmax & 1023u);
          deathv[dying] = ev;
          unresolved = false;
        }
        __threadfence_block();
        merged += (int)__popcll(__ballot(win));
        if (merged >= target) break;
      }
    }
    __threadfence_block();

    // landscape features: top-2 tents over minima per t (lanes 0..24)
    if (lane < TPTS) {
      float ti = (float)((double)lane * (100.0 / 24.0));
      float t1 = 0.f, t2 = 0.f;
      for (int ii = 0; ii < mcnt; ii++) {
        int m = mlist[ii];
        float tent = fminf(ti - val_s[m], deathv[m] - ti);
        tent = fmaxf(tent, 0.f);
        if (tent > t1)      { t2 = t1; t1 = tent; }
        else if (tent > t2) { t2 = tent; }
      }
      feats[b * NFEAT + lane]        = t1;
      feats[b * NFEAT + TPTS + lane] = t2;
    }
  }

  // ---- last block computes the dense head ----
  __threadfence();
  __syncthreads();
  if (tid == 0) last_sh = (atomicAdd(done_ctr, 1) == BATCH - 1) ? 1 : 0;
  __syncthreads();
  if (!last_sh) return;
  __threadfence();

  for (int idx = tid; idx < BATCH * OUTF; idx += BT2) {
    int bb = idx / OUTF, ff = idx % OUTF;
    float acc = b_land[ff];
    const float* wr = w_land + ff * NFEAT;
    const float* fr = feats + bb * NFEAT;
    for (int j = 0; j < NFEAT; j++) acc += fr[j] * wr[j];
    xt_s[idx] = acc;
  }
  __syncthreads();
  if (tid < OUTF) {
    float s = 0.f;
    for (int bb = 0; bb < BATCH; bb++) s += fabsf(xt_s[bb * OUTF + tid]);
    out[BATCH * NCLS + tid] = s;
  }
  for (int idx = tid; idx < BATCH * NCLS; idx += BT2) {
    int bb = idx / NCLS, cc = idx % NCLS;
    float acc = b_fc[cc];
    const float* wr = w_fc + cc * OUTF;
    const float* xr = xt_s + bb * OUTF;
    for (int ff = 0; ff < OUTF; ff++) acc += fmaxf(xr[ff], 0.f) * wr[ff];
    out[bb * NCLS + cc] = acc;
  }
}

// ---------------------------------------------------------------------------
extern "C" void kernel_launch(void* const* d_in, const int* in_sizes, int n_in,
                              void* d_out, int out_size, void* d_ws, size_t ws_size,
                              hipStream_t stream) {
  (void)in_sizes; (void)n_in; (void)out_size; (void)ws_size;
  const float* x      = (const float*)d_in[0];   // [32,1,28,28]
  const float* w_land = (const float*)d_in[1];   // [50,50]
  const float* b_land = (const float*)d_in[2];   // [50]
  const float* w_fc   = (const float*)d_in[3];   // [10,50]
  const float* b_fc   = (const float*)d_in[4];   // [10]
  float* out   = (float*)d_out;                  // [32*10] out then [50] signal
  float* v     = (float*)d_ws;                   // [32*784]
  float* feats = v + BATCH * G784;               // [32*50]
  int*   done  = (int*)(feats + BATCH * NFEAT);  // [1]

  dim3 g1(BATCH, NBX);
  dtm_kernel<<<g1, BT, 0, stream>>>(x, v, done);
  pd0_kernel<<<BATCH, BT2, 0, stream>>>(v, feats, done,
                                        w_land, b_land, w_fc, b_fc, out);
}

// Round 7
// 102.120 us; speedup vs baseline: 1.4407x; 1.0057x over previous
//
#include <hip/hip_runtime.h>
#include <math.h>

// Problem constants
#define H28 28
#define G784 784
#define BATCH 32
#define NOFF 3025   // 55*55 lattice offsets (|di|,|dj| <= 27)
#define NOFFP 3072  // padded to multiple of 64
#define NKEY 1459   // keys di*di+dj*dj in [0, 1458]
#define TPTS 25
#define KMAX 2
#define NFEAT 50    // KMAX*TPTS
#define OUTF 50
#define NCLS 10

#define NBX 28      // blocks per batch for dtm
#define BT 512      // threads per dtm block (8 waves)
#define BT2 512     // pd0 block: 8 waves
#define HS 2048     // edge-dedup hash slots (pow2)
#define EMAX 1024   // deduped edge capacity

typedef unsigned long long u64;

// ---------------------------------------------------------------------------
// Compile-time counting-sorted offset table. d2 reproduces
// f32(sqrt(key)*(224/27))^2 via constexpr Newton sqrt in double.
// ---------------------------------------------------------------------------
struct OffPair { unsigned ij; float d2; };
struct OffTab  { OffPair e[NOFFP]; };

constexpr double csqrt(double x) {
  double r = x * 0.5 + 1.0;
  for (int i = 0; i < 20; i++) r = 0.5 * (r + x / r);
  return r;
}

constexpr OffTab make_offtab() {
  OffTab t{};
  int start[NKEY] = {};
  for (int i = 0; i < NOFF; i++) {
    int di = i / 55 - 27, dj = i % 55 - 27;
    start[di * di + dj * dj]++;
  }
  int run = 0;
  for (int k = 0; k < NKEY; k++) { int h = start[k]; start[k] = run; run += h; }
  for (int i = 0; i < NOFF; i++) {
    int di = i / 55 - 27, dj = i % 55 - 27;
    int key = di * di + dj * dj;
    int pos = start[key]++;
    float sd = (key == 0) ? 0.0f : (float)(csqrt((double)key) * (224.0 / 27.0));
    t.e[pos].ij = ((unsigned)(di & 0xffff)) | (((unsigned)(dj & 0xffff)) << 16);
    t.e[pos].d2 = sd * sd;
  }
  for (int i = NOFF; i < NOFFP; i++) { t.e[i].ij = 0x00640064u; t.e[i].d2 = 0.f; }
  return t;
}

__device__ constexpr OffTab OFFTAB = make_offtab();

// ---------------------------------------------------------------------------
// wave64 inclusive scan via DPP (row_shr 1,2,4,8; row_bcast15/31).
// ---------------------------------------------------------------------------
__device__ __forceinline__ float wave_iscan_f32(float x) {
  int t;
  t = __builtin_amdgcn_update_dpp(0, __float_as_int(x), 0x111, 0xf, 0xf, true);
  x += __int_as_float(t);
  t = __builtin_amdgcn_update_dpp(0, __float_as_int(x), 0x112, 0xf, 0xf, true);
  x += __int_as_float(t);
  t = __builtin_amdgcn_update_dpp(0, __float_as_int(x), 0x114, 0xf, 0xf, true);
  x += __int_as_float(t);
  t = __builtin_amdgcn_update_dpp(0, __float_as_int(x), 0x118, 0xf, 0xf, true);
  x += __int_as_float(t);
  t = __builtin_amdgcn_update_dpp(0, __float_as_int(x), 0x142, 0xa, 0xf, true);
  x += __int_as_float(t);
  t = __builtin_amdgcn_update_dpp(0, __float_as_int(x), 0x143, 0xc, 0xf, true);
  x += __int_as_float(t);
  return x;
}

// ---------------------------------------------------------------------------
// Kernel 1: DTM (unchanged). grid=(BATCH,NBX), block=BT.
// ---------------------------------------------------------------------------
__global__ __launch_bounds__(BT) void dtm_kernel(const float* __restrict__ x,
                                                 float* __restrict__ v,
                                                 int* __restrict__ done_ctr) {
  __shared__ float w_s[G784];
  __shared__ float red[BT / 64];

  const int tid  = threadIdx.x;
  const int b    = blockIdx.x;
  const int bx   = blockIdx.y;
  const int wave = tid >> 6;
  const int lane = tid & 63;

  if (b == 0 && bx == 0 && tid == 0) *done_ctr = 0;

  float ps = 0.f;
  for (int i = tid; i < G784; i += BT) {
    float wv = x[b * G784 + i];
    w_s[i] = wv;
    ps += wv;
  }
  for (int off = 32; off > 0; off >>= 1) ps += __shfl_xor(ps, off);
  if (lane == 0) red[wave] = ps;
  __syncthreads();
  float tot = 0.f;
  for (int k = 0; k < BT / 64; k++) tot += red[k];
  const float bound = 0.2f * tot;

  const int slot = bx * 8 + wave;

  for (int g = slot; g < G784; g += NBX * 8) {
    const int i1 = g / H28, j1 = g % H28;
    float cw = 0.f, cwd = 0.f;
    float cwp = 0.f, cwdp = 0.f, dk2 = 0.f;
    bool crossed = false;
    int o = lane;
    unsigned ij = OFFTAB.e[o].ij;
    float d2v   = OFFTAB.e[o].d2;
    for (int base = 0; base < NOFFP && !crossed; base += 64) {
      int onext = o + 64;
      if (onext >= NOFFP) onext = o;
      const unsigned ij_n = OFFTAB.e[onext].ij;
      const float    d2_n = OFFTAB.e[onext].d2;
      const int di = (short)(ij & 0xffffu);
      const int dj = (short)(ij >> 16);
      const int i2 = i1 + di, j2 = j1 + dj;
      const bool inb = ((unsigned)i2 < (unsigned)H28) & ((unsigned)j2 < (unsigned)H28);
      const float wv = inb ? w_s[i2 * H28 + j2] : 0.f;
      const float wd = wv * d2v;
      const float psw = wave_iscan_f32(wv);
      const float psd = wave_iscan_f32(wd);
      const u64 mask = __ballot(cw + psw >= bound);
      if (mask) {
        const int f = __ffsll((u64)mask) - 1;
        const float psw_f = __shfl(psw, f);
        const float w_f   = __shfl(wv, f);
        const float psd_f = __shfl(psd, f);
        const float wd_f  = __shfl(wd, f);
        dk2  = __shfl(d2v, f);
        cwp  = cw + (psw_f - w_f);
        cwdp = cwd + (psd_f - wd_f);
        crossed = true;
      } else {
        cw  += __int_as_float(__builtin_amdgcn_readlane(__float_as_int(psw), 63));
        cwd += __int_as_float(__builtin_amdgcn_readlane(__float_as_int(psd), 63));
      }
      ij = ij_n; d2v = d2_n; o = onext;
    }
    const float val = (cwdp + (bound - cwp) * dk2) / bound;
    if (lane == 0) v[b * G784 + g] = sqrtf(fmaxf(val, 0.f));
  }
}

// ---------------------------------------------------------------------------
// Kernel 2: pd0 + landscape + (last block) dense head. grid=BATCH, block=512.
// Phases: [forest from global] B [chase-to-root publish + minima init] B
// [edge collect+hash] B [compact] B [rank sort] B [wave0 Kruskal] B
// [landscape partials (all waves)] B [combine + feats] [tail: head].
// ---------------------------------------------------------------------------
__device__ __forceinline__ u64 pix_key(const float* val_s, int p) {
  return (((u64)__float_as_uint(val_s[p])) << 10) | (unsigned)p;
}

__global__ __launch_bounds__(BT2) void pd0_kernel(const float* __restrict__ v,
                                                  float* __restrict__ feats,
                                                  int* __restrict__ done_ctr,
                                                  const float* __restrict__ w_land,
                                                  const float* __restrict__ b_land,
                                                  const float* __restrict__ w_fc,
                                                  const float* __restrict__ b_fc,
                                                  float* __restrict__ out) {
  __shared__ float val_s[G784];
  __shared__ int   ptr_s[G784];
  __shared__ int   parent[G784];     // minima entries only
  __shared__ unsigned rank_s[G784];  // minima entries only
  __shared__ unsigned claims[G784];  // minima entries only
  __shared__ float deathv[G784];     // minima entries only
  __shared__ int   mlist[G784];
  __shared__ u64   oldkey[G784];     // minima entries only
  __shared__ unsigned htag[HS];
  __shared__ u64   hval[HS];         // hash vals; reused as sorted edges
  __shared__ u64   edges[EMAX];
  __shared__ float redf[BT2 / 64];
  __shared__ float lt1[8][32];       // per-wave landscape partials
  __shared__ float lt2[8][32];
  __shared__ int   mcnt_sh, ecnt_sh, last_sh;
  __shared__ float xt_s[BATCH * OUTF];

  const int tid  = threadIdx.x;
  const int b    = blockIdx.x;
  const int wave = tid >> 6;
  const int lane = tid & 63;
  if (tid == 0) { mcnt_sh = 0; ecnt_sh = 0; }
  __syncthreads();                               // B0: counters visible

  // --- phase 1: forest from GLOBAL reads (L1/L2-hot); minima; hash init ---
  const float* vb = v + b * G784;
  float pm = -1e30f;
  for (int p = tid; p < G784; p += BT2) {
    int i = p / H28, j = p % H28;
    float vp = vb[p];
    val_s[p] = vp;
    pm = fmaxf(pm, vp);
    u64 bk = (((u64)__float_as_uint(vp)) << 10) | (unsigned)p;
    int best = p;
    if (i > 0) {
      int q = p - H28; u64 kq = (((u64)__float_as_uint(vb[q])) << 10) | (unsigned)q;
      if (kq < bk) { bk = kq; best = q; }
    }
    if (i < H28 - 1) {
      int q = p + H28; u64 kq = (((u64)__float_as_uint(vb[q])) << 10) | (unsigned)q;
      if (kq < bk) { bk = kq; best = q; }
    }
    if (j > 0) {
      int q = p - 1; u64 kq = (((u64)__float_as_uint(vb[q])) << 10) | (unsigned)q;
      if (kq < bk) { bk = kq; best = q; }
    }
    if (j < H28 - 1) {
      int q = p + 1; u64 kq = (((u64)__float_as_uint(vb[q])) << 10) | (unsigned)q;
      if (kq < bk) { bk = kq; best = q; }
    }
    ptr_s[p] = best;
    if (best == p) { int mi = atomicAdd(&mcnt_sh, 1); mlist[mi] = p; }
  }
  for (int i = tid; i < HS; i += BT2) { htag[i] = 0u; hval[i] = ~0ULL; }
  for (int off = 32; off > 0; off >>= 1) pm = fmaxf(pm, __shfl_xor(pm, off));
  if (lane == 0) redf[wave] = pm;
  __syncthreads();                               // B1: forest complete

  float vmax = redf[0];
  for (int k = 1; k < BT2 / 64; k++) vmax = fmaxf(vmax, redf[k]);
  const int mcnt = mcnt_sh;

  // --- phase 2: lock-free chase-to-root + publish; minima UF init ---
  for (int p = tid; p < G784; p += BT2) {
    int x = ptr_s[p];
    int y = ptr_s[x];
    while (y != x) { x = y; y = ptr_s[x]; }     // races benign: see analysis
    ptr_s[p] = x;
  }
  for (int i = tid; i < mcnt; i += BT2) {
    int m = mlist[i];
    parent[m] = m;
    rank_s[m] = 0u;
    claims[m] = 0xFFFFFFFFu;
    deathv[m] = vmax;
    oldkey[m] = pix_key(val_s, m);
  }
  __syncthreads();                               // B2: labels + UF ready

  // --- phase 3: cross-basin edges -> hash dedup (per-pair min key) ---
  for (int p = tid; p < G784; p += BT2) {
    u64 kp = pix_key(val_s, p);
    int i = p / H28, j = p % H28;
    int nbs[4];
    nbs[0] = (i > 0)       ? p - H28 : -1;
    nbs[1] = (i < H28 - 1) ? p + H28 : -1;
    nbs[2] = (j > 0)       ? p - 1   : -1;
    nbs[3] = (j < H28 - 1) ? p + 1   : -1;
    int bp = ptr_s[p];
    for (int t = 0; t < 4; t++) {
      int q = nbs[t];
      if (q >= 0) {
        u64 kq = pix_key(val_s, q);
        int bq = ptr_s[q];
        if (kq < kp && bq != bp) {
          u64 key = (((u64)__float_as_uint(val_s[p])) << 32) |
                    (((u64)(unsigned)p) << 22) |
                    (((u64)(unsigned)t) << 20) |
                    (((u64)(unsigned)bp) << 10) |
                    ((u64)(unsigned)bq);
          unsigned lo = (bp < bq) ? (unsigned)bp : (unsigned)bq;
          unsigned hi = (bp < bq) ? (unsigned)bq : (unsigned)bp;
          unsigned pairid = (lo << 10) | hi;
          unsigned idx = (pairid * 2654435761u) >> 21;   // HS=2048
          for (;;) {
            unsigned t0 = atomicCAS(&htag[idx], 0u, pairid + 1u);
            if (t0 == 0u || t0 == pairid + 1u) { atomicMin(&hval[idx], key); break; }
            idx = (idx + 1) & (HS - 1);
          }
        }
      }
    }
  }
  __syncthreads();                               // B3: hash complete

  // --- phase 4: compact hash -> edges ---
  for (int i = tid; i < HS; i += BT2) {
    if (htag[i]) {
      int e = atomicAdd(&ecnt_sh, 1);
      if (e < EMAX) edges[e] = hval[i];
    }
  }
  __syncthreads();                               // B4: edges ready
  const int ne = (ecnt_sh < EMAX) ? ecnt_sh : EMAX;

  // --- phase 5: full-block rank sort (unique keys; broadcast LDS reads) ---
  {
    u64 m0 = 0, m1 = 0;
    int r0 = 0, r1 = 0;
    const int i0 = tid, i1 = tid + BT2;
    const bool h0 = (i0 < ne), h1 = (i1 < ne);
    if (h0) m0 = edges[i0];
    if (h1) m1 = edges[i1];
    for (int j = 0; j < ne; j++) {
      u64 ej = edges[j];
      r0 += (ej < m0) ? 1 : 0;
      r1 += (ej < m1) ? 1 : 0;
    }
    if (h0) hval[r0] = m0;
    if (h1) hval[r1] = m1;
  }
  __syncthreads();                               // B5: sorted
  const u64* sedges = hval;

  // --- phase 6: wave0 claim-based Kruskal (sequential-order exact) ---
  if (wave == 0) {
    int merged = 0;
    const int target = mcnt - 1;
    for (int base = 0; base < ne && merged < target; base += 64) {
      const int idx = base + lane;
      bool unresolved = (idx < ne);
      const u64 e = unresolved ? sedges[idx] : 0ULL;
      const int A  = (int)((e >> 10) & 1023u);
      const int Bq = (int)(e & 1023u);
      const float ev = __uint_as_float((unsigned)(e >> 32));
      for (;;) {
        int rA = A, rB = Bq;
        if (unresolved) {
          int xx = A;
          for (;;) { int p1 = parent[xx]; if (p1 == xx) break;
                     int p2 = parent[p1]; parent[xx] = p2; xx = p2; }
          rA = xx;
          xx = Bq;
          for (;;) { int p1 = parent[xx]; if (p1 == xx) break;
                     int p2 = parent[p1]; parent[xx] = p2; xx = p2; }
          rB = xx;
        }
        bool crossing = unresolved && (rA != rB);
        if (unresolved && !crossing) unresolved = false;
        if (__ballot(crossing) == 0ULL) break;
        if (crossing) {
          atomicMin(&claims[rA], (unsigned)lane);
          atomicMin(&claims[rB], (unsigned)lane);
        }
        __threadfence_block();
        bool win = crossing && claims[rA] == (unsigned)lane
                            && claims[rB] == (unsigned)lane;
        __threadfence_block();
        if (crossing) { claims[rA] = 0xFFFFFFFFu; claims[rB] = 0xFFFFFFFFu; }
        if (win) {
          u64 ka = oldkey[rA], kb = oldkey[rB];
          unsigned ra_ = rank_s[rA], rb_ = rank_s[rB];
          int big   = (ra_ > rb_) ? rA : ((rb_ > ra_) ? rB : ((rA < rB) ? rA : rB));
          int small = (big == rA) ? rB : rA;
          parent[small] = big;
          if (ra_ == rb_) rank_s[big] = ra_ + 1u;
          u64 okmin = (ka < kb) ? ka : kb;
          u64 okmax = (ka < kb) ? kb : ka;
          oldkey[big] = okmin;
          int dying = (int)(okmax & 1023u);
          deathv[dying] = ev;
          unresolved = false;
        }
        __threadfence_block();
        merged += (int)__popcll(__ballot(win));
        if (merged >= target) break;
      }
    }
  }
  __syncthreads();                               // B6: deaths final

  // --- phase 7: landscape partials, all 8 waves over minima slices ---
  {
    float ti = (lane < TPTS) ? (float)((double)lane * (100.0 / 24.0)) : 0.f;
    float t1 = 0.f, t2 = 0.f;
    for (int ii = wave; ii < mcnt; ii += 8) {
      int m = mlist[ii];
      float birth = val_s[m];
      float death = deathv[m];
      float tent = fmaxf(fminf(ti - birth, death - ti), 0.f);
      if (tent > t1)      { t2 = t1; t1 = tent; }
      else if (tent > t2) { t2 = tent; }
    }
    if (lane < TPTS) { lt1[wave][lane] = t1; lt2[wave][lane] = t2; }
  }
  __syncthreads();                               // B7: partials ready

  if (wave == 0 && lane < TPTS) {
    float t1 = 0.f, t2 = 0.f;
    for (int w = 0; w < 8; w++) {
      float a1 = lt1[w][lane], a2 = lt2[w][lane];
      float nt1 = fmaxf(t1, a1);
      float nt2 = fmaxf(fminf(t1, a1), fmaxf(t2, a2));
      t1 = nt1; t2 = nt2;
    }
    feats[b * NFEAT + lane]        = t1;
    feats[b * NFEAT + TPTS + lane] = t2;
  }

  // ---- tail: last block computes the dense head ----
  __threadfence();
  __syncthreads();
  if (tid == 0) last_sh = (atomicAdd(done_ctr, 1) == BATCH - 1) ? 1 : 0;
  __syncthreads();
  if (!last_sh) return;
  __threadfence();

  for (int idx = tid; idx < BATCH * OUTF; idx += BT2) {
    int bb = idx / OUTF, ff = idx % OUTF;
    float acc = b_land[ff];
    const float* wr = w_land + ff * NFEAT;
    const float* fr = feats + bb * NFEAT;
    for (int j = 0; j < NFEAT; j++) acc += fr[j] * wr[j];
    xt_s[idx] = acc;
  }
  __syncthreads();
  if (tid < OUTF) {
    float s = 0.f;
    for (int bb = 0; bb < BATCH; bb++) s += fabsf(xt_s[bb * OUTF + tid]);
    out[BATCH * NCLS + tid] = s;
  }
  for (int idx = tid; idx < BATCH * NCLS; idx += BT2) {
    int bb = idx / NCLS, cc = idx % NCLS;
    float acc = b_fc[cc];
    const float* wr = w_fc + cc * OUTF;
    const float* xr = xt_s + bb * OUTF;
    for (int ff = 0; ff < OUTF; ff++) acc += fmaxf(xr[ff], 0.f) * wr[ff];
    out[bb * NCLS + cc] = acc;
  }
}

// ---------------------------------------------------------------------------
extern "C" void kernel_launch(void* const* d_in, const int* in_sizes, int n_in,
                              void* d_out, int out_size, void* d_ws, size_t ws_size,
                              hipStream_t stream) {
  (void)in_sizes; (void)n_in; (void)out_size; (void)ws_size;
  const float* x      = (const float*)d_in[0];   // [32,1,28,28]
  const float* w_land = (const float*)d_in[1];   // [50,50]
  const float* b_land = (const float*)d_in[2];   // [50]
  const float* w_fc   = (const float*)d_in[3];   // [10,50]
  const float* b_fc   = (const float*)d_in[4];   // [10]
  float* out   = (float*)d_out;                  // [32*10] out then [50] signal
  float* v     = (float*)d_ws;                   // [32*784]
  float* feats = v + BATCH * G784;               // [32*50]
  int*   done  = (int*)(feats + BATCH * NFEAT);  // [1]

  dim3 g1(BATCH, NBX);
  dtm_kernel<<<g1, BT, 0, stream>>>(x, v, done);
  pd0_kernel<<<BATCH, BT2, 0, stream>>>(v, feats, done,
                                        w_land, b_land, w_fc, b_fc, out);
}